// Round 4
// baseline (199.249 us; speedup 1.0000x reference)
//
#include <hip/hip_runtime.h>
#include <hip/hip_bf16.h>
#include <cstdint>

typedef __bf16 bf16x8 __attribute__((ext_vector_type(8)));
typedef float f32x4 __attribute__((ext_vector_type(4)));

__device__ __forceinline__ unsigned short f2b(float f) {
  __bf16 h = (__bf16)f;
  return __builtin_bit_cast(unsigned short, h);
}

__device__ __forceinline__ void gload_lds16(const void* g, void* l) {
  __builtin_amdgcn_global_load_lds(
      (__attribute__((address_space(1))) void*)g,
      (__attribute__((address_space(3))) void*)l,
      16, 0, 0);
}

// ---------------- fp32 -> bf16 elementwise convert ----------------
__global__ void cvt_f32_bf16(const float* __restrict__ in,
                             unsigned short* __restrict__ out, int n) {
  int i = (blockIdx.x * blockDim.x + threadIdx.x) * 4;
  if (i + 3 < n) {
    float4 f = *(const float4*)&in[i];
    ushort4 u = make_ushort4(f2b(f.x), f2b(f.y), f2b(f.z), f2b(f.w));
    *(ushort4*)&out[i] = u;
  }
}

// ---------------- fp32 [R][C] -> bf16 [C][R] transpose-convert ----------------
__global__ void transpose_cvt(const float* __restrict__ in,
                              unsigned short* __restrict__ out, int R, int C) {
  __shared__ float tile[32][33];
  int c0 = blockIdx.x * 32, r0 = blockIdx.y * 32;
  int x = threadIdx.x, y = threadIdx.y;
  #pragma unroll
  for (int j = y; j < 32; j += 8)
    tile[j][x] = in[(size_t)(r0 + j) * C + c0 + x];
  __syncthreads();
  #pragma unroll
  for (int j = y; j < 32; j += 8)
    out[(size_t)(c0 + j) * R + r0 + x] = f2b(tile[x][j]);
}

// ---------------- V transpose per head: qkv V-part -> Vt[bh][64][1024] ----------------
__global__ void transpose_v(const unsigned short* __restrict__ qkv,
                            unsigned short* __restrict__ vt) {
  __shared__ unsigned short tile[32][33];
  int bh = blockIdx.x, s0 = blockIdx.y * 32, d0 = blockIdx.z * 32;
  int b = bh >> 4, h = bh & 15;
  int x = threadIdx.x, y = threadIdx.y;
  #pragma unroll
  for (int j = y; j < 32; j += 8)
    tile[j][x] = qkv[(size_t)(b * 1024 + s0 + j) * 3072 + 2048 + h * 64 + d0 + x];
  __syncthreads();
  #pragma unroll
  for (int j = y; j < 32; j += 8)
    vt[(size_t)(bh * 64 + d0 + j) * 1024 + s0 + x] = tile[x][j];
}

// ---------------- bf16 GEMM, Bt input: C[M][N] = A[M][K] @ Bt[N][K]^T + bias ----------------
template <int OUT_F32>
__global__ __launch_bounds__(256, 2)
void gemm_bt(const unsigned short* __restrict__ A,
             const unsigned short* __restrict__ Bt,
             const float* __restrict__ bias, void* __restrict__ C,
             int M, int N, int K) {
  __shared__ __align__(16) unsigned short sA[128 * 32];
  __shared__ __align__(16) unsigned short sB[128 * 32];
  const int t = threadIdx.x;
  const int w = t >> 6, lane = t & 63;
  const int ln = lane & 15, lq = lane >> 4;
  const int wr = w >> 1, wc = w & 1;
  const int m0 = blockIdx.y * 128, n0 = blockIdx.x * 128;

  f32x4 acc[4][4];
  #pragma unroll
  for (int i = 0; i < 4; i++)
    #pragma unroll
    for (int j = 0; j < 4; j++) acc[i][j] = (f32x4){0.f, 0.f, 0.f, 0.f};

  for (int k0 = 0; k0 < K; k0 += 32) {
    __syncthreads();
    #pragma unroll
    for (int i = 0; i < 2; ++i) {
      int idx = i * 256 + t;
      int row = idx >> 2;        // 64B per row = 4 chunks of 16B
      int cb = (idx & 3) * 8;    // ushort offset
      gload_lds16(A + (size_t)(m0 + row) * K + k0 + cb, &sA[idx * 8]);
    }
    #pragma unroll
    for (int i = 0; i < 2; ++i) {
      int idx = i * 256 + t;
      int row = idx >> 2;
      int cb = (idx & 3) * 8;
      gload_lds16(Bt + (size_t)(n0 + row) * K + k0 + cb, &sB[idx * 8]);
    }
    __syncthreads();
    bf16x8 af[4], bfr[4];
    #pragma unroll
    for (int m = 0; m < 4; m++)
      af[m] = *(const bf16x8*)&sA[(wr * 64 + m * 16 + ln) * 32 + lq * 8];
    #pragma unroll
    for (int n = 0; n < 4; n++)
      bfr[n] = *(const bf16x8*)&sB[(wc * 64 + n * 16 + ln) * 32 + lq * 8];
    #pragma unroll
    for (int m = 0; m < 4; m++)
      #pragma unroll
      for (int n = 0; n < 4; n++)
        acc[m][n] = __builtin_amdgcn_mfma_f32_16x16x32_bf16(af[m], bfr[n], acc[m][n], 0, 0, 0);
  }

  #pragma unroll
  for (int m = 0; m < 4; m++) {
    #pragma unroll
    for (int n = 0; n < 4; n++) {
      int col = n0 + wc * 64 + n * 16 + ln;
      float bv = bias[col];
      #pragma unroll
      for (int r = 0; r < 4; r++) {
        int row = m0 + wr * 64 + m * 16 + lq * 4 + r;
        float v = acc[m][n][r] + bv;
        if (OUT_F32)
          ((float*)C)[(size_t)row * N + col] = v;
        else
          ((unsigned short*)C)[(size_t)row * N + col] = f2b(v);
      }
    }
  }
}

// ---------------- flash attention, barrier-free ----------------
// Fragments for Q, K, V are read DIRECTLY from global (L2-resident: 256 KB
// K/V per (b,h), shared by 16 q-blocks). Only LDS use is the per-wave P
// tile (2 KB/wave) -> no __syncthreads anywhere; 4 waves/block run free.
// Swapped QK^T: S^T = mfma(K,Q) puts q on the lane axis (q = ln), k
// in-register -> k-reduce = 15 in-lane ops + 2 shfl.  Softmax in
// log2-domain (exp2), T13 defer-max, T5 setprio around MFMA.
__global__ __launch_bounds__(256, 4)
void attn_fwd(const unsigned short* __restrict__ qkv,
              const unsigned short* __restrict__ vt,
              unsigned short* __restrict__ aout) {
  const int b = blockIdx.z, h = blockIdx.y, q0 = blockIdx.x * 64;
  __shared__ __align__(16) unsigned short sP[4][16 * 64];
  const int t = threadIdx.x;
  const int w = t >> 6, lane = t & 63;
  const int ln = lane & 15, lq = lane >> 4;
  const float K2 = 0.125f * 1.44269504f;   // scale * log2(e)
  const float THR = 11.54f;                // defer-max threshold (8 nats in log2)

  const unsigned short* qp = qkv + (size_t)(b * 1024 + q0 + w * 16) * 3072 + h * 64;
  const unsigned short* kp = qkv + (size_t)(b * 1024) * 3072 + 1024 + h * 64;
  const unsigned short* vp = vt + (size_t)((b * 16 + h) * 64) * 1024;

  // Q fragments direct from global: row = ln (within wave's 16), col chunk c*4+lq
  bf16x8 qf[2];
  #pragma unroll
  for (int c = 0; c < 2; c++)
    qf[c] = *(const bf16x8*)&qp[(size_t)ln * 3072 + (c * 4 + lq) * 8];

  f32x4 o[4];
  float mrow = -1e30f, lsum = 0.f;
  #pragma unroll
  for (int n = 0; n < 4; n++) o[n] = (f32x4){0.f, 0.f, 0.f, 0.f};

  for (int kt = 0; kt < 16; ++kt) {
    const int kv0 = kt * 64;

    // V fragments issued early (used after softmax, ~long latency window)
    bf16x8 vf[4][2];
    #pragma unroll
    for (int n = 0; n < 4; n++)
      #pragma unroll
      for (int c2 = 0; c2 < 2; c2++)
        vf[n][c2] = *(const bf16x8*)&vp[(size_t)(n * 16 + ln) * 1024 + kv0 + c2 * 32 + lq * 8];

    // QK^T swapped: lane holds q = ln, k = kc*16 + lq*4 + reg
    f32x4 st[4];
    #pragma unroll
    for (int kc = 0; kc < 4; kc++) {
      const unsigned short* kr = &kp[(size_t)(kv0 + kc * 16 + ln) * 3072];
      bf16x8 k0f = *(const bf16x8*)&kr[lq * 8];
      bf16x8 k1f = *(const bf16x8*)&kr[32 + lq * 8];
      __builtin_amdgcn_s_setprio(1);
      st[kc] = __builtin_amdgcn_mfma_f32_16x16x32_bf16(k0f, qf[0], (f32x4){0.f, 0.f, 0.f, 0.f}, 0, 0, 0);
      st[kc] = __builtin_amdgcn_mfma_f32_16x16x32_bf16(k1f, qf[1], st[kc], 0, 0, 0);
      __builtin_amdgcn_s_setprio(0);
    }

    // softmax over k in log2 domain (in-lane 16 values + 2 shfl)
    float xv[4][4];
    float tm = -1e30f;
    #pragma unroll
    for (int kc = 0; kc < 4; kc++) {
      #pragma unroll
      for (int r = 0; r < 4; r++) {
        xv[kc][r] = st[kc][r] * K2;
        tm = fmaxf(tm, xv[kc][r]);
      }
    }
    tm = fmaxf(tm, __shfl_xor(tm, 16));
    tm = fmaxf(tm, __shfl_xor(tm, 32));

    // T13 defer-max: only rescale when the running max actually grows
    if (!__all(tm <= mrow + THR)) {
      float mn = fmaxf(mrow, tm);
      float al = exp2f(mrow - mn);
      mrow = mn;
      lsum *= al;
      #pragma unroll
      for (int r = 0; r < 4; r++) {
        float alr = __shfl(al, (lane & 48) | (lq * 4 + r));
        #pragma unroll
        for (int n = 0; n < 4; n++) o[n][r] *= alr;
      }
    }

    float ts = 0.f;
    #pragma unroll
    for (int kc = 0; kc < 4; kc++) {
      #pragma unroll
      for (int r = 0; r < 4; r++) {
        xv[kc][r] = exp2f(xv[kc][r] - mrow);
        ts += xv[kc][r];
      }
    }
    ts += __shfl_xor(ts, 16);
    ts += __shfl_xor(ts, 32);
    lsum += ts;

    // P -> per-wave LDS (swizzled): lane writes k = kc*16 + lq*4..+3, row q = ln
    unsigned char* pb = (unsigned char*)sP[w];
    #pragma unroll
    for (int kc = 0; kc < 4; kc++) {
      ushort4 u = make_ushort4(f2b(xv[kc][0]), f2b(xv[kc][1]),
                               f2b(xv[kc][2]), f2b(xv[kc][3]));
      int boff = (kc * 32 + lq * 8) ^ ((ln & 7) << 4);
      *(ushort4*)(pb + ln * 128 + boff) = u;
    }

    // PV: O += P @ V  (A = P[16 q][64 k]; B^T = Vt rows d)
    #pragma unroll
    for (int c2 = 0; c2 < 2; c2++) {
      bf16x8 pa = *(const bf16x8*)&sP[w][ln * 64 + ((c2 * 4 + lq) ^ (ln & 7)) * 8];
      __builtin_amdgcn_s_setprio(1);
      #pragma unroll
      for (int n = 0; n < 4; n++)
        o[n] = __builtin_amdgcn_mfma_f32_16x16x32_bf16(pa, vf[n][c2], o[n], 0, 0, 0);
      __builtin_amdgcn_s_setprio(0);
    }
  }

  // epilogue: divide by l (lsum lives on lane ln == q-row), store bf16
  float linv[4];
  #pragma unroll
  for (int r = 0; r < 4; r++)
    linv[r] = 1.f / __shfl(lsum, (lane & 48) | (lq * 4 + r));
  #pragma unroll
  for (int n = 0; n < 4; n++) {
    #pragma unroll
    for (int r = 0; r < 4; r++) {
      int row = q0 + w * 16 + lq * 4 + r;
      int col = h * 64 + n * 16 + ln;
      aout[(size_t)(b * 1024 + row) * 1024 + col] = f2b(o[n][r] * linv[r]);
    }
  }
}

extern "C" void kernel_launch(void* const* d_in, const int* in_sizes, int n_in,
                              void* d_out, int out_size, void* d_ws, size_t ws_size,
                              hipStream_t stream) {
  const float* x = (const float*)d_in[0];
  const float* W_qkv = (const float*)d_in[1];
  const float* b_qkv = (const float*)d_in[2];
  const float* W_out = (const float*)d_in[3];
  const float* b_out = (const float*)d_in[4];
  float* out = (float*)d_out;

  char* ws = (char*)d_ws;
  // layout (bytes): xb 8MB | WqkvT 6MB | WoutT 2MB | qkv 24MB | Vt 8MB | aout 8MB
  unsigned short* xb    = (unsigned short*)(ws);
  unsigned short* wqkvT = (unsigned short*)(ws + 8388608);
  unsigned short* woutT = (unsigned short*)(ws + 14680064);
  unsigned short* qkv   = (unsigned short*)(ws + 16777216);
  unsigned short* vt    = (unsigned short*)(ws + 41943040);
  unsigned short* aout  = (unsigned short*)(ws + 50331648);
  if (ws_size < 58720256) return;  // insufficient scratch -> loud failure

  cvt_f32_bf16<<<4096, 256, 0, stream>>>(x, xb, 4096 * 1024);
  transpose_cvt<<<dim3(96, 32), dim3(32, 8), 0, stream>>>(W_qkv, wqkvT, 1024, 3072);
  transpose_cvt<<<dim3(32, 32), dim3(32, 8), 0, stream>>>(W_out, woutT, 1024, 1024);
  gemm_bt<0><<<dim3(24, 32), 256, 0, stream>>>(xb, wqkvT, b_qkv, qkv, 4096, 3072, 1024);
  transpose_v<<<dim3(64, 32, 2), dim3(32, 8), 0, stream>>>(qkv, vt);
  attn_fwd<<<dim3(16, 16, 4), 256, 0, stream>>>(qkv, vt, aout);
  gemm_bt<1><<<dim3(8, 32), 256, 0, stream>>>(aout, woutT, b_out, out, 4096, 1024, 1024);
}

// Round 5
// 126.095 us; speedup vs baseline: 1.5801x; 1.5801x over previous
//
#include <hip/hip_runtime.h>
#include <hip/hip_bf16.h>
#include <cstdint>

typedef __bf16 bf16x8 __attribute__((ext_vector_type(8)));
typedef float f32x4 __attribute__((ext_vector_type(4)));

__device__ __forceinline__ unsigned short f2b(float f) {
  __bf16 h = (__bf16)f;
  return __builtin_bit_cast(unsigned short, h);
}

__device__ __forceinline__ void gload_lds16(const void* g, void* l) {
  __builtin_amdgcn_global_load_lds(
      (__attribute__((address_space(1))) void*)g,
      (__attribute__((address_space(3))) void*)l,
      16, 0, 0);
}

// ---------------- fp32 -> bf16 elementwise convert ----------------
__global__ void cvt_f32_bf16(const float* __restrict__ in,
                             unsigned short* __restrict__ out, int n) {
  int i = (blockIdx.x * blockDim.x + threadIdx.x) * 4;
  if (i + 3 < n) {
    float4 f = *(const float4*)&in[i];
    ushort4 u = make_ushort4(f2b(f.x), f2b(f.y), f2b(f.z), f2b(f.w));
    *(ushort4*)&out[i] = u;
  }
}

// ---------------- fp32 [R][C] -> bf16 [C][R] transpose-convert ----------------
__global__ void transpose_cvt(const float* __restrict__ in,
                              unsigned short* __restrict__ out, int R, int C) {
  __shared__ float tile[32][33];
  int c0 = blockIdx.x * 32, r0 = blockIdx.y * 32;
  int x = threadIdx.x, y = threadIdx.y;
  #pragma unroll
  for (int j = y; j < 32; j += 8)
    tile[j][x] = in[(size_t)(r0 + j) * C + c0 + x];
  __syncthreads();
  #pragma unroll
  for (int j = y; j < 32; j += 8)
    out[(size_t)(c0 + j) * R + r0 + x] = f2b(tile[x][j]);
}

// ---------------- V transpose per head: qkv V-part -> Vt[bh][64][1024] ----------------
__global__ void transpose_v(const unsigned short* __restrict__ qkv,
                            unsigned short* __restrict__ vt) {
  __shared__ unsigned short tile[32][33];
  int bh = blockIdx.x, s0 = blockIdx.y * 32, d0 = blockIdx.z * 32;
  int b = bh >> 4, h = bh & 15;
  int x = threadIdx.x, y = threadIdx.y;
  #pragma unroll
  for (int j = y; j < 32; j += 8)
    tile[j][x] = qkv[(size_t)(b * 1024 + s0 + j) * 3072 + 2048 + h * 64 + d0 + x];
  __syncthreads();
  #pragma unroll
  for (int j = y; j < 32; j += 8)
    vt[(size_t)(bh * 64 + d0 + j) * 1024 + s0 + x] = tile[x][j];
}

// ---------------- bf16 GEMM, Bt input, 2-phase double-buffered LDS ----------------
// C[M][N] = A[M][K] @ Bt[N][K]^T + bias.  Per K-step: issue next-tile
// global_load_lds FIRST, then ds_read+MFMA current tile, then one
// vmcnt(0)+barrier (T3-minimum; stage latency hides under MFMA).
template <int OUT_F32>
__global__ __launch_bounds__(256, 2)
void gemm_bt(const unsigned short* __restrict__ A,
             const unsigned short* __restrict__ Bt,
             const float* __restrict__ bias, void* __restrict__ C,
             int M, int N, int K) {
  __shared__ __align__(16) unsigned short sA[2][128 * 32];
  __shared__ __align__(16) unsigned short sB[2][128 * 32];
  const int t = threadIdx.x;
  const int w = t >> 6, lane = t & 63;
  const int ln = lane & 15, lq = lane >> 4;
  const int wr = w >> 1, wc = w & 1;
  const int m0 = blockIdx.y * 128, n0 = blockIdx.x * 128;

  f32x4 acc[4][4];
  #pragma unroll
  for (int i = 0; i < 4; i++)
    #pragma unroll
    for (int j = 0; j < 4; j++) acc[i][j] = (f32x4){0.f, 0.f, 0.f, 0.f};

  auto stage = [&](int buf, int k0) {
    #pragma unroll
    for (int i = 0; i < 2; ++i) {
      int idx = i * 256 + t;
      int row = idx >> 2;        // 64B per row = 4 chunks of 16B
      int cb = (idx & 3) * 8;    // ushort offset
      gload_lds16(A + (size_t)(m0 + row) * K + k0 + cb, &sA[buf][idx * 8]);
    }
    #pragma unroll
    for (int i = 0; i < 2; ++i) {
      int idx = i * 256 + t;
      int row = idx >> 2;
      int cb = (idx & 3) * 8;
      gload_lds16(Bt + (size_t)(n0 + row) * K + k0 + cb, &sB[buf][idx * 8]);
    }
  };

  stage(0, 0);
  asm volatile("s_waitcnt vmcnt(0)" ::: "memory");
  __builtin_amdgcn_s_barrier();

  const int nk = K >> 5;
  for (int ki = 0; ki < nk; ++ki) {
    const int cur = ki & 1;
    if (ki + 1 < nk) stage(cur ^ 1, (ki + 1) << 5);

    bf16x8 af[4], bfr[4];
    #pragma unroll
    for (int m = 0; m < 4; m++)
      af[m] = *(const bf16x8*)&sA[cur][(wr * 64 + m * 16 + ln) * 32 + lq * 8];
    #pragma unroll
    for (int n = 0; n < 4; n++)
      bfr[n] = *(const bf16x8*)&sB[cur][(wc * 64 + n * 16 + ln) * 32 + lq * 8];
    __builtin_amdgcn_s_setprio(1);
    #pragma unroll
    for (int m = 0; m < 4; m++)
      #pragma unroll
      for (int n = 0; n < 4; n++)
        acc[m][n] = __builtin_amdgcn_mfma_f32_16x16x32_bf16(af[m], bfr[n], acc[m][n], 0, 0, 0);
    __builtin_amdgcn_s_setprio(0);

    asm volatile("s_waitcnt vmcnt(0)" ::: "memory");
    __builtin_amdgcn_s_barrier();
  }

  #pragma unroll
  for (int m = 0; m < 4; m++) {
    #pragma unroll
    for (int n = 0; n < 4; n++) {
      int col = n0 + wc * 64 + n * 16 + ln;
      float bv = bias[col];
      #pragma unroll
      for (int r = 0; r < 4; r++) {
        int row = m0 + wr * 64 + m * 16 + lq * 4 + r;
        float v = acc[m][n][r] + bv;
        if (OUT_F32)
          ((float*)C)[(size_t)row * N + col] = v;
        else
          ((unsigned short*)C)[(size_t)row * N + col] = f2b(v);
      }
    }
  }
}

// ---------------- flash attention ----------------
// R2 structure (proven 45 us): double-buffered LDS K/V via global_load_lds,
// XOR-swizzle, swapped QK^T (S^T = mfma(K,Q): lane q = ln, k in-register).
// Softmax in log2 domain with folded scale; T13 defer-max; T5 setprio.
// LDS: 4 x 8KB buffers (Q stage reused as V-odd) + per-wave P = 40 KB.
// Swizzle rule: (row, col) of a [R][64] ushort tile at byte
//   row*128 + ((col*2) ^ ((row&7)<<4));  gload_lds source pre-swizzled.
__global__ __launch_bounds__(256, 4)
void attn_fwd(const unsigned short* __restrict__ qkv,
              const unsigned short* __restrict__ vt,
              unsigned short* __restrict__ aout) {
  const int b = blockIdx.z, h = blockIdx.y, q0 = blockIdx.x * 64;
  __shared__ __align__(16) unsigned short sB[4][64 * 64];
  __shared__ __align__(16) unsigned short sP[4][16 * 64];
  const int t = threadIdx.x;
  const int w = t >> 6, lane = t & 63;
  const int ln = lane & 15, lq = lane >> 4;
  const float K2 = 0.125f * 1.44269504f;   // scale * log2(e)
  const float THR = 11.54f;                // defer-max threshold (8 nats)

  const size_t qbase = (size_t)(b * 1024 + q0) * 3072 + h * 64;
  const size_t kbase = (size_t)(b * 1024) * 3072 + 1024 + h * 64;
  const size_t vbase = (size_t)((b * 16 + h) * 64) * 1024;

  // prologue: stage Q -> sB[0], K0 -> sB[1], V0 -> sB[2]
  #pragma unroll
  for (int i = 0; i < 2; i++) {
    int idx = i * 256 + t;
    int row = idx >> 3, ch = idx & 7;
    int sw = (ch ^ (row & 7)) * 8;
    gload_lds16(qkv + qbase + (size_t)row * 3072 + sw, &sB[0][idx * 8]);
    gload_lds16(qkv + kbase + (size_t)row * 3072 + sw, &sB[1][idx * 8]);
    gload_lds16(vt + vbase + (size_t)row * 1024 + sw, &sB[2][idx * 8]);
  }
  __syncthreads();
  bf16x8 qf[2];
  #pragma unroll
  for (int c = 0; c < 2; c++) {
    int row = w * 16 + ln;
    qf[c] = *(const bf16x8*)&sB[0][row * 64 + ((c * 4 + lq) ^ (ln & 7)) * 8];
  }
  __syncthreads();  // qf reads done before sB[0] is reused for V-odd

  f32x4 o[4];
  float mrow = -1e30f, lsum = 0.f;
  #pragma unroll
  for (int n = 0; n < 4; n++) o[n] = (f32x4){0.f, 0.f, 0.f, 0.f};

  for (int kt = 0; kt < 16; ++kt) {
    const unsigned short* kb = sB[(kt & 1) ? 3 : 1];
    const unsigned short* vb = sB[(kt & 1) ? 0 : 2];
    if (kt < 15) {
      const int kv1 = (kt + 1) * 64;
      unsigned short* kn = sB[(kt & 1) ? 1 : 3];
      unsigned short* vn = sB[(kt & 1) ? 2 : 0];
      #pragma unroll
      for (int i = 0; i < 2; i++) {
        int idx = i * 256 + t;
        int row = idx >> 3, ch = idx & 7;
        int sw = (ch ^ (row & 7)) * 8;
        gload_lds16(qkv + kbase + (size_t)(kv1 + row) * 3072 + sw, &kn[idx * 8]);
        gload_lds16(vt + vbase + (size_t)row * 1024 + kv1 + sw, &vn[idx * 8]);
      }
    }

    // QK^T swapped: st[kc] = S^T block, lane holds q=ln, k = kc*16 + lq*4 + reg
    f32x4 st[4];
    #pragma unroll
    for (int kc = 0; kc < 4; kc++) {
      int krow = kc * 16 + ln;
      bf16x8 k0f = *(const bf16x8*)&kb[krow * 64 + ((0 + lq) ^ (ln & 7)) * 8];
      bf16x8 k1f = *(const bf16x8*)&kb[krow * 64 + ((4 + lq) ^ (ln & 7)) * 8];
      __builtin_amdgcn_s_setprio(1);
      st[kc] = __builtin_amdgcn_mfma_f32_16x16x32_bf16(k0f, qf[0], (f32x4){0.f, 0.f, 0.f, 0.f}, 0, 0, 0);
      st[kc] = __builtin_amdgcn_mfma_f32_16x16x32_bf16(k1f, qf[1], st[kc], 0, 0, 0);
      __builtin_amdgcn_s_setprio(0);
    }

    // softmax over k in log2 domain (in-lane 16 values + 2 shfl)
    float xv[4][4];
    float tm = -1e30f;
    #pragma unroll
    for (int kc = 0; kc < 4; kc++) {
      #pragma unroll
      for (int r = 0; r < 4; r++) {
        xv[kc][r] = st[kc][r] * K2;
        tm = fmaxf(tm, xv[kc][r]);
      }
    }
    tm = fmaxf(tm, __shfl_xor(tm, 16));
    tm = fmaxf(tm, __shfl_xor(tm, 32));

    // T13 defer-max: only rescale when the running max actually grows
    if (!__all(tm <= mrow + THR)) {
      float mn = fmaxf(mrow, tm);
      float al = exp2f(mrow - mn);
      mrow = mn;
      lsum *= al;
      #pragma unroll
      for (int r = 0; r < 4; r++) {
        float alr = __shfl(al, (lane & 48) | (lq * 4 + r));
        #pragma unroll
        for (int n = 0; n < 4; n++) o[n][r] *= alr;
      }
    }

    float ts = 0.f;
    #pragma unroll
    for (int kc = 0; kc < 4; kc++) {
      #pragma unroll
      for (int r = 0; r < 4; r++) {
        xv[kc][r] = exp2f(xv[kc][r] - mrow);
        ts += xv[kc][r];
      }
    }
    ts += __shfl_xor(ts, 16);
    ts += __shfl_xor(ts, 32);
    lsum += ts;

    // P -> LDS: lane writes 4 bf16 (k = kc*16 + lq*4 .. +3) for row q = ln
    unsigned char* pb = (unsigned char*)sP[w];
    #pragma unroll
    for (int kc = 0; kc < 4; kc++) {
      ushort4 u = make_ushort4(f2b(xv[kc][0]), f2b(xv[kc][1]),
                               f2b(xv[kc][2]), f2b(xv[kc][3]));
      int boff = (kc * 32 + lq * 8) ^ ((ln & 7) << 4);
      *(ushort4*)(pb + ln * 128 + boff) = u;
    }

    // PV: O += P @ V  (A = P[16 q][64 k]; B^T = Vt rows dv)
    #pragma unroll
    for (int c2 = 0; c2 < 2; c2++) {
      bf16x8 pa = *(const bf16x8*)&sP[w][ln * 64 + ((c2 * 4 + lq) ^ (ln & 7)) * 8];
      __builtin_amdgcn_s_setprio(1);
      #pragma unroll
      for (int n = 0; n < 4; n++) {
        int vrow = n * 16 + ln;
        bf16x8 vf = *(const bf16x8*)&vb[vrow * 64 + ((c2 * 4 + lq) ^ (ln & 7)) * 8];
        o[n] = __builtin_amdgcn_mfma_f32_16x16x32_bf16(pa, vf, o[n], 0, 0, 0);
      }
      __builtin_amdgcn_s_setprio(0);
    }

    asm volatile("s_waitcnt vmcnt(0)" ::: "memory");
    __builtin_amdgcn_s_barrier();
  }

  // epilogue: divide by l (lsum lives on lane ln == q-row), store bf16
  float linv[4];
  #pragma unroll
  for (int r = 0; r < 4; r++)
    linv[r] = 1.f / __shfl(lsum, (lane & 48) | (lq * 4 + r));
  #pragma unroll
  for (int n = 0; n < 4; n++) {
    #pragma unroll
    for (int r = 0; r < 4; r++) {
      int row = q0 + w * 16 + lq * 4 + r;
      int col = h * 64 + n * 16 + ln;
      aout[(size_t)(b * 1024 + row) * 1024 + col] = f2b(o[n][r] * linv[r]);
    }
  }
}

extern "C" void kernel_launch(void* const* d_in, const int* in_sizes, int n_in,
                              void* d_out, int out_size, void* d_ws, size_t ws_size,
                              hipStream_t stream) {
  const float* x = (const float*)d_in[0];
  const float* W_qkv = (const float*)d_in[1];
  const float* b_qkv = (const float*)d_in[2];
  const float* W_out = (const float*)d_in[3];
  const float* b_out = (const float*)d_in[4];
  float* out = (float*)d_out;

  char* ws = (char*)d_ws;
  // layout (bytes): xb 8MB | WqkvT 6MB | WoutT 2MB | qkv 24MB | Vt 8MB | aout 8MB
  unsigned short* xb    = (unsigned short*)(ws);
  unsigned short* wqkvT = (unsigned short*)(ws + 8388608);
  unsigned short* woutT = (unsigned short*)(ws + 14680064);
  unsigned short* qkv   = (unsigned short*)(ws + 16777216);
  unsigned short* vt    = (unsigned short*)(ws + 41943040);
  unsigned short* aout  = (unsigned short*)(ws + 50331648);
  if (ws_size < 58720256) return;  // insufficient scratch -> loud failure

  cvt_f32_bf16<<<4096, 256, 0, stream>>>(x, xb, 4096 * 1024);
  transpose_cvt<<<dim3(96, 32), dim3(32, 8), 0, stream>>>(W_qkv, wqkvT, 1024, 3072);
  transpose_cvt<<<dim3(32, 32), dim3(32, 8), 0, stream>>>(W_out, woutT, 1024, 1024);
  gemm_bt<0><<<dim3(24, 32), 256, 0, stream>>>(xb, wqkvT, b_qkv, qkv, 4096, 3072, 1024);
  transpose_v<<<dim3(64, 32, 2), dim3(32, 8), 0, stream>>>(qkv, vt);
  attn_fwd<<<dim3(16, 16, 4), 256, 0, stream>>>(qkv, vt, aout);
  gemm_bt<1><<<dim3(8, 32), 256, 0, stream>>>(aout, woutT, b_out, out, 4096, 1024, 1024);
}